// Round 5
// baseline (239.704 us; speedup 1.0000x reference)
//
#include <hip/hip_runtime.h>
#include <math.h>

// KabschLoss: loss = mean( (xc @ R - yc)^2 ), R = U Vh from SVD of C = xc^T yc.
// Identity: sum |xc R - yc|^2 = Sx + Sy - 2*nuclear_norm(C)  (R orthogonal,
// tr(R^T C) = sum of singular values). So we only need per-batch raw moments
// and the singular values of the 3x3 covariance (closed-form eig of C^T C).
//
// V6: line-touch fix. V1/V3/V5 all plateau at ~2.6 TB/s effective because
// their strided per-lane layouts make each wave-instruction touch 3-4x more
// distinct 64B cache lines than it consumes (8-16B used per line per instr;
// the same lines are re-touched by sibling instructions). Model: ~4 cyc per
// distinct-line-touch per CU fits V1 (147k vs 180k cyc) and V5 (196k vs 204k).
// Fix: load each point as one 12-B dwordx3; 16 consecutive lanes = one
// contiguous 192-B, 3-line-aligned run, fully consumed by that instruction.
// Line redundancy 4x -> 1.0x (copy-equal) with zero repacking: each lane
// holds complete points. No LDS staging, no inline asm, no raw barriers.

#define NPTS 128
#define BPB 16   // batches per 256-thread block (16 lanes per batch)

struct f3 { float a, b, c; };   // 12-byte point; loads as global_load_dwordx3

__device__ __forceinline__ float xsum(float v, int m) {
    return v + __shfl_xor(v, m);
}

__global__ __launch_bounds__(256, 8) void kabsch_kernel(
        const float* __restrict__ x, const float* __restrict__ y,
        float* __restrict__ out, float scale) {
    const int tid  = threadIdx.x;
    const int lane = tid & 63;
    const int wave = tid >> 6;
    const int sub  = tid & 15;            // lane within 16-lane batch group
    const int b    = blockIdx.x * BPB + (tid >> 4);

    // Lane handles points {sub + 16*s : s=0..7} of batch b. At step s the 16
    // lanes of the group read points [16s, 16s+16) = bytes [192s, 192s+192)
    // of the batch -- contiguous and 64B-line-aligned (192 = 3 lines).
    const f3* xb = (const f3*)(x + (size_t)b * (NPTS * 3));
    const f3* yb = (const f3*)(y + (size_t)b * (NPTS * 3));

    // 17 per-lane accumulators (raw moments)
    float sx0=0.f,sx1=0.f,sx2=0.f, sy0=0.f,sy1=0.f,sy2=0.f;
    float qx=0.f, qy=0.f;
    float c00=0.f,c01=0.f,c02=0.f,c10=0.f,c11=0.f,c12=0.f,c20=0.f,c21=0.f,c22=0.f;

#define ACC(px0,px1,px2,py0,py1,py2) do {                                    \
        sx0+=(px0); sx1+=(px1); sx2+=(px2);                                  \
        sy0+=(py0); sy1+=(py1); sy2+=(py2);                                  \
        qx = fmaf((px0),(px0),fmaf((px1),(px1),fmaf((px2),(px2),qx)));       \
        qy = fmaf((py0),(py0),fmaf((py1),(py1),fmaf((py2),(py2),qy)));       \
        c00=fmaf((px0),(py0),c00); c01=fmaf((px0),(py1),c01); c02=fmaf((px0),(py2),c02); \
        c10=fmaf((px1),(py0),c10); c11=fmaf((px1),(py1),c11); c12=fmaf((px1),(py2),c12); \
        c20=fmaf((px2),(py0),c20); c21=fmaf((px2),(py1),c21); c22=fmaf((px2),(py2),c22); \
    } while (0)

    #pragma unroll
    for (int s = 0; s < 8; ++s) {
        const int p = s * 16 + sub;
        const f3 px = xb[p];
        const f3 py = yb[p];
        ACC(px.a, px.b, px.c,  py.a, py.b, py.c);
    }
#undef ACC

    // Butterfly reduce the 17 sums within each 16-lane group (masks 1,2,4,8).
    #pragma unroll
    for (int m = 1; m <= 8; m <<= 1) {
        sx0=xsum(sx0,m); sx1=xsum(sx1,m); sx2=xsum(sx2,m);
        sy0=xsum(sy0,m); sy1=xsum(sy1,m); sy2=xsum(sy2,m);
        qx =xsum(qx ,m); qy =xsum(qy ,m);
        c00=xsum(c00,m); c01=xsum(c01,m); c02=xsum(c02,m);
        c10=xsum(c10,m); c11=xsum(c11,m); c12=xsum(c12,m);
        c20=xsum(c20,m); c21=xsum(c21,m); c22=xsum(c22,m);
    }
    // Now every lane in a group holds its batch's full sums.

    const float invN = 1.0f / (float)NPTS;
    // Mean-centered covariance C = Sxy - sx sy^T / N
    float C00 = c00 - sx0*sy0*invN, C01 = c01 - sx0*sy1*invN, C02 = c02 - sx0*sy2*invN;
    float C10 = c10 - sx1*sy0*invN, C11 = c11 - sx1*sy1*invN, C12 = c12 - sx1*sy2*invN;
    float C20 = c20 - sx2*sy0*invN, C21 = c21 - sx2*sy1*invN, C22 = c22 - sx2*sy2*invN;
    float Sx = qx - (sx0*sx0 + sx1*sx1 + sx2*sx2) * invN;
    float Sy = qy - (sy0*sy0 + sy1*sy1 + sy2*sy2) * invN;

    // A = C^T C (symmetric PSD); closed-form eigenvalues (trigonometric).
    float a00 = C00*C00 + C10*C10 + C20*C20;
    float a01 = C00*C01 + C10*C11 + C20*C21;
    float a02 = C00*C02 + C10*C12 + C20*C22;
    float a11 = C01*C01 + C11*C11 + C21*C21;
    float a12 = C01*C02 + C11*C12 + C21*C22;
    float a22 = C02*C02 + C12*C12 + C22*C22;

    float q = (a00 + a11 + a22) * (1.0f / 3.0f);
    float b00 = a00 - q, b11 = a11 - q, b22 = a22 - q;
    float p2 = (b00*b00 + b11*b11 + b22*b22
                + 2.0f * (a01*a01 + a02*a02 + a12*a12)) * (1.0f / 6.0f);
    float p = sqrtf(fmaxf(p2, 0.0f));
    float detB = b00 * (b11*b22 - a12*a12)
               - a01 * (a01*b22 - a12*a02)
               + a02 * (a01*a12 - b11*a02);
    float p3 = p * p * p;
    float r = (p3 > 1e-30f) ? (0.5f * detB / p3) : 0.0f;
    r = fminf(1.0f, fmaxf(-1.0f, r));
    float phi = acosf(r) * (1.0f / 3.0f);
    float two_p = 2.0f * p;
    float l1 = q + two_p * cosf(phi);                        // largest
    float l3 = q + two_p * cosf(phi + 2.0943951023931953f);  // smallest
    float l2 = 3.0f * q - l1 - l3;
    float nuc = sqrtf(fmaxf(l1, 0.0f)) + sqrtf(fmaxf(l2, 0.0f)) + sqrtf(fmaxf(l3, 0.0f));

    float term = Sx + Sy - 2.0f * nuc;

    // Sum the 4 distinct group terms across the wave (masks 16,32).
    term += __shfl_xor(term, 16);
    term += __shfl_xor(term, 32);

    __shared__ float wsum[4];
    if (lane == 0) wsum[wave] = term;
    __syncthreads();
    if (tid == 0) {
        float t = (wsum[0] + wsum[1] + wsum[2] + wsum[3]) * scale;
        atomicAdd(out, t);
    }
}

extern "C" void kernel_launch(void* const* d_in, const int* in_sizes, int n_in,
                              void* d_out, int out_size, void* d_ws, size_t ws_size,
                              hipStream_t stream) {
    const float* x = (const float*)d_in[0];
    const float* y = (const float*)d_in[1];
    float* out = (float*)d_out;

    const int B = in_sizes[0] / (NPTS * 3);   // 65536
    const float scale = 1.0f / ((float)B * (float)NPTS * 3.0f);

    hipMemsetAsync(out, 0, sizeof(float), stream);   // harness poisons d_out
    const int blocks = B / BPB;                      // 4096 blocks, 256 threads
    kabsch_kernel<<<blocks, 256, 0, stream>>>(x, y, out, scale);
}

// Round 6
// 214.797 us; speedup vs baseline: 1.1160x; 1.1160x over previous
//
#include <hip/hip_runtime.h>
#include <math.h>

// KabschLoss: loss = mean( (xc @ R - yc)^2 ), R = U Vh from SVD of C = xc^T yc.
// Identity: sum |xc R - yc|^2 = Sx + Sy - 2*nuclear_norm(C)  (R orthogonal,
// tr(R^T C) = sum of singular values). So we only need per-batch raw moments
// and the singular values of the 3x3 covariance (closed-form eig of C^T C).
//
// V7 (= V4 re-run; V4 was never measured -- its round had 1000s+ infra stalls).
// Evidence so far: V5's warm replay ran 85us with 0.13 MB of HBM traffic ->
// the kernel is NOT HBM-bound; the plateau is redundant 64B-line touches in
// the L1/L2 request path (strided per-lane reads touch each line 3-4x, reuse
// distance >> 32KB L1, ~4-5 cyc/touch/CU fits V1 and V5). V6's dwordx3 probe
// was invalidated by scratch traffic (WRITE_SIZE 78 MB -- struct loads went
// through the stack). Only fix: copy-shaped staging. Every global
// wave-instruction here is a contiguous aligned 1 KB (line redundancy 1.0x);
// compute reads LDS in the old 48-B pattern, values/order identical to V3.
// Plain HIP only: no inline asm, no global_load_lds, no raw barriers.

#define NPTS 128
#define BPB 32                       // batches per block
#define CPTS 32                      // points per batch per chunk
#define NCH (NPTS / CPTS)            // 4 chunks
#define CHB (CPTS * 12)              // 384 B per batch per chunk (unpadded)
#define BSTRIDE 400                  // padded per-batch chunk bytes in LDS
#define ARR_BYTES (BPB * BSTRIDE)    // 12800 B (one array's chunk)
#define BUF_BYTES (2 * ARR_BYTES)    // 25600 B (x + y)

__device__ __forceinline__ float xsum(float v, int m) {
    return v + __shfl_xor(v, m);
}

__global__ __launch_bounds__(256) void kabsch_kernel(
        const float* __restrict__ x, const float* __restrict__ y,
        float* __restrict__ out, float scale) {
    __shared__ char lds[2 * BUF_BYTES];   // 51200 B double buffer
    __shared__ float wsum[4];

    const int tid  = threadIdx.x;
    const int lane = tid & 63;
    const int wave = tid >> 6;
    const int sub  = lane & 7;    // lane within 8-lane batch group
    const int gb   = tid >> 3;    // batch-in-block 0..31 (== wave*8 + (lane>>3))

    const size_t b0 = (size_t)blockIdx.x * BPB;
    const char* xB0 = (const char*)(x + b0 * (NPTS * 3));
    const char* yB0 = (const char*)(y + b0 * (NPTS * 3));

    // Staging plan: 6 float4 per thread per chunk. Piece jj (0..2 = x, 3..5 = y)
    // reads global byte i = tid*16 + (jj%3)*4096 of the 12 KB chunk image --
    // each wave-instruction covers a contiguous, aligned 1 KB (line-complete).
    // LDS destination is the padded batch-major layout (batch bt at bt*BSTRIDE).
    const char* srcb[6];
    int         ldso[6];
    #pragma unroll
    for (int jj = 0; jj < 6; ++jj) {
        const int jx  = (jj < 3) ? jj : jj - 3;
        const int i   = tid * 16 + jx * 4096;      // 0..12272
        const int bt  = i / CHB;                   // batch-in-block 0..31
        const int rem = i - bt * CHB;              // 0..383, 16B-aligned
        srcb[jj] = ((jj < 3) ? xB0 : yB0) + (size_t)bt * (NPTS * 12) + rem;
        ldso[jj] = ((jj < 3) ? 0 : ARR_BYTES) + bt * BSTRIDE + rem;
    }

    // 17 per-lane accumulators (raw moments)
    float sx0=0.f,sx1=0.f,sx2=0.f, sy0=0.f,sy1=0.f,sy2=0.f;
    float qx=0.f, qy=0.f;
    float c00=0.f,c01=0.f,c02=0.f,c10=0.f,c11=0.f,c12=0.f,c20=0.f,c21=0.f,c22=0.f;

#define ACC(px0,px1,px2,py0,py1,py2) do {                                    \
        sx0+=(px0); sx1+=(px1); sx2+=(px2);                                  \
        sy0+=(py0); sy1+=(py1); sy2+=(py2);                                  \
        qx = fmaf((px0),(px0),fmaf((px1),(px1),fmaf((px2),(px2),qx)));       \
        qy = fmaf((py0),(py0),fmaf((py1),(py1),fmaf((py2),(py2),qy)));       \
        c00=fmaf((px0),(py0),c00); c01=fmaf((px0),(py1),c01); c02=fmaf((px0),(py2),c02); \
        c10=fmaf((px1),(py0),c10); c11=fmaf((px1),(py1),c11); c12=fmaf((px1),(py2),c12); \
        c20=fmaf((px2),(py0),c20); c21=fmaf((px2),(py1),c21); c22=fmaf((px2),(py2),c22); \
    } while (0)

    // Prologue: stage chunk 0 into buffer 0.
    {
        float4 st[6];
        #pragma unroll
        for (int jj = 0; jj < 6; ++jj) st[jj] = *(const float4*)(srcb[jj]);
        #pragma unroll
        for (int jj = 0; jj < 6; ++jj) *(float4*)(lds + ldso[jj]) = st[jj];
    }

    #pragma unroll
    for (int c = 0; c < NCH; ++c) {
        __syncthreads();   // staged chunk c visible; prior reads of wb done
        const int rb = (c & 1) ? BUF_BYTES : 0;
        const int wb = (c & 1) ? 0 : BUF_BYTES;

        // Issue next chunk's global loads BEFORE compute: HBM latency hides
        // under the FMA phase. st[] indices are compile-time (full unroll) ->
        // registers, no scratch.
        float4 st[6];
        if (c + 1 < NCH) {
            #pragma unroll
            for (int jj = 0; jj < 6; ++jj)
                st[jj] = *(const float4*)(srcb[jj] + (c + 1) * CHB);
        }

        // Compute chunk c: lane (gb, sub) handles points 4*sub .. 4*sub+3
        // of batch gb (chunk offset c*32 points) -- same values & order as V3.
        const char* xp = lds + rb + gb * BSTRIDE + sub * 48;
        const char* yp = xp + ARR_BYTES;
        const float4 q0 = *(const float4*)(xp);
        const float4 q1 = *(const float4*)(xp + 16);
        const float4 q2 = *(const float4*)(xp + 32);
        const float4 r0 = *(const float4*)(yp);
        const float4 r1 = *(const float4*)(yp + 16);
        const float4 r2 = *(const float4*)(yp + 32);
        ACC(q0.x, q0.y, q0.z,  r0.x, r0.y, r0.z);
        ACC(q0.w, q1.x, q1.y,  r0.w, r1.x, r1.y);
        ACC(q1.z, q1.w, q2.x,  r1.z, r1.w, r2.x);
        ACC(q2.y, q2.z, q2.w,  r2.y, r2.z, r2.w);

        if (c + 1 < NCH) {
            #pragma unroll
            for (int jj = 0; jj < 6; ++jj)
                *(float4*)(lds + wb + ldso[jj]) = st[jj];
        }
    }
#undef ACC

    // Butterfly reduce the 17 sums within each 8-lane group (masks 1,2,4).
    #pragma unroll
    for (int m = 1; m <= 4; m <<= 1) {
        sx0=xsum(sx0,m); sx1=xsum(sx1,m); sx2=xsum(sx2,m);
        sy0=xsum(sy0,m); sy1=xsum(sy1,m); sy2=xsum(sy2,m);
        qx =xsum(qx ,m); qy =xsum(qy ,m);
        c00=xsum(c00,m); c01=xsum(c01,m); c02=xsum(c02,m);
        c10=xsum(c10,m); c11=xsum(c11,m); c12=xsum(c12,m);
        c20=xsum(c20,m); c21=xsum(c21,m); c22=xsum(c22,m);
    }
    // Now every lane in a group holds its batch's full sums.

    const float invN = 1.0f / (float)NPTS;
    // Mean-centered covariance C = Sxy - sx sy^T / N
    float C00 = c00 - sx0*sy0*invN, C01 = c01 - sx0*sy1*invN, C02 = c02 - sx0*sy2*invN;
    float C10 = c10 - sx1*sy0*invN, C11 = c11 - sx1*sy1*invN, C12 = c12 - sx1*sy2*invN;
    float C20 = c20 - sx2*sy0*invN, C21 = c21 - sx2*sy1*invN, C22 = c22 - sx2*sy2*invN;
    float Sx = qx - (sx0*sx0 + sx1*sx1 + sx2*sx2) * invN;
    float Sy = qy - (sy0*sy0 + sy1*sy1 + sy2*sy2) * invN;

    // A = C^T C (symmetric PSD); closed-form eigenvalues (trigonometric).
    float a00 = C00*C00 + C10*C10 + C20*C20;
    float a01 = C00*C01 + C10*C11 + C20*C21;
    float a02 = C00*C02 + C10*C12 + C20*C22;
    float a11 = C01*C01 + C11*C11 + C21*C21;
    float a12 = C01*C02 + C11*C12 + C21*C22;
    float a22 = C02*C02 + C12*C12 + C22*C22;

    float q = (a00 + a11 + a22) * (1.0f / 3.0f);
    float b00 = a00 - q, b11 = a11 - q, b22 = a22 - q;
    float p2 = (b00*b00 + b11*b11 + b22*b22
                + 2.0f * (a01*a01 + a02*a02 + a12*a12)) * (1.0f / 6.0f);
    float p = sqrtf(fmaxf(p2, 0.0f));
    float detB = b00 * (b11*b22 - a12*a12)
               - a01 * (a01*b22 - a12*a02)
               + a02 * (a01*a12 - b11*a02);
    float p3 = p * p * p;
    float r = (p3 > 1e-30f) ? (0.5f * detB / p3) : 0.0f;
    r = fminf(1.0f, fmaxf(-1.0f, r));
    float phi = acosf(r) * (1.0f / 3.0f);
    float two_p = 2.0f * p;
    float l1 = q + two_p * cosf(phi);                        // largest
    float l3 = q + two_p * cosf(phi + 2.0943951023931953f);  // smallest
    float l2 = 3.0f * q - l1 - l3;
    float nuc = sqrtf(fmaxf(l1, 0.0f)) + sqrtf(fmaxf(l2, 0.0f)) + sqrtf(fmaxf(l3, 0.0f));

    float term = Sx + Sy - 2.0f * nuc;

    // Sum the 8 distinct group terms across the wave (masks 8,16,32).
    term += __shfl_xor(term, 8);
    term += __shfl_xor(term, 16);
    term += __shfl_xor(term, 32);

    if (lane == 0) wsum[wave] = term;
    __syncthreads();
    if (tid == 0) {
        float t = (wsum[0] + wsum[1] + wsum[2] + wsum[3]) * scale;
        atomicAdd(out, t);
    }
}

extern "C" void kernel_launch(void* const* d_in, const int* in_sizes, int n_in,
                              void* d_out, int out_size, void* d_ws, size_t ws_size,
                              hipStream_t stream) {
    const float* x = (const float*)d_in[0];
    const float* y = (const float*)d_in[1];
    float* out = (float*)d_out;

    const int B = in_sizes[0] / (NPTS * 3);   // 65536
    const float scale = 1.0f / ((float)B * (float)NPTS * 3.0f);

    hipMemsetAsync(out, 0, sizeof(float), stream);   // harness poisons d_out
    const int blocks = B / BPB;                      // 2048 blocks, 256 threads
    kabsch_kernel<<<blocks, 256, 0, stream>>>(x, y, out, scale);
}

// Round 7
// 211.554 us; speedup vs baseline: 1.1331x; 1.0153x over previous
//
#include <hip/hip_runtime.h>
#include <math.h>

// KabschLoss: loss = mean( (xc @ R - yc)^2 ), R = U Vh from SVD of C = xc^T yc.
// Identity: sum |xc R - yc|^2 = Sx + Sy - 2*nuclear_norm(C)  (R orthogonal,
// tr(R^T C) = sum of singular values). So we only need per-batch raw moments
// and the singular values of the 3x3 covariance (closed-form eig of C^T C).
//
// V8 = V1 restored (the session's measured best: 74.4us dispatch, 212us bench).
// Ceiling evidence from V1/V3/V5/V7: five structurally independent kernels
// (occupancy 33-65%, load width 8B/16B, window depth 2-12, strided vs
// copy-shaped vs LDS-staged) all deliver 2.3-2.7 TB/s read with VALU ~10%,
// MFMA 0, LDS 0. This is the read-only stream ceiling (~80-100 outstanding
// 64B lines/CU x 64B / ~500ns ~= 2.5-3 TB/s; m13's 6.3 TB/s copy = RD+WR,
// i.e. ~3.15 TB/s read-side). The 201 MB of reads are irreducible for a full
// reduction, so duration floor ~= 201.3MB / 2.7TB/s ~= 74us -- V1 sits on it.

#define NPTS 128

__device__ __forceinline__ float xsum(float v, int m) {
    return v + __shfl_xor(v, m);
}

__global__ __launch_bounds__(256) void kabsch_kernel(
        const float* __restrict__ x, const float* __restrict__ y,
        float* __restrict__ out, float scale) {
    const int tid  = threadIdx.x;
    const int lane = tid & 63;
    const int wave = tid >> 6;
    const int g    = lane >> 3;   // group of 8 lanes -> one batch
    const int sub  = lane & 7;    // lane within group
    const int b    = blockIdx.x * 32 + wave * 8 + g;

    const float* xb = x + (size_t)b * (NPTS * 3);
    const float* yb = y + (size_t)b * (NPTS * 3);

    // 17 per-lane accumulators (raw moments)
    float sx0=0.f,sx1=0.f,sx2=0.f, sy0=0.f,sy1=0.f,sy2=0.f;
    float qx=0.f, qy=0.f;
    float c00=0.f,c01=0.f,c02=0.f,c10=0.f,c11=0.f,c12=0.f,c20=0.f,c21=0.f,c22=0.f;

    // Each lane handles 8 pairs of consecutive points: i0 = sub*2 + s*16.
    // 6 consecutive floats per array per step, 8-byte aligned -> 3x float2.
    #pragma unroll
    for (int s = 0; s < 8; ++s) {
        const int i0 = sub * 2 + s * 16;
        const float2* xp = (const float2*)(xb + i0 * 3);
        const float2* yp = (const float2*)(yb + i0 * 3);
        float2 xA = xp[0], xB = xp[1], xC = xp[2];
        float2 yA = yp[0], yB = yp[1], yC = yp[2];

        // point 0: (xA.x, xA.y, xB.x) ; point 1: (xB.y, xC.x, xC.y)
        {
            float px0=xA.x, px1=xA.y, px2=xB.x;
            float py0=yA.x, py1=yA.y, py2=yB.x;
            sx0+=px0; sx1+=px1; sx2+=px2;
            sy0+=py0; sy1+=py1; sy2+=py2;
            qx = fmaf(px0,px0,fmaf(px1,px1,fmaf(px2,px2,qx)));
            qy = fmaf(py0,py0,fmaf(py1,py1,fmaf(py2,py2,qy)));
            c00=fmaf(px0,py0,c00); c01=fmaf(px0,py1,c01); c02=fmaf(px0,py2,c02);
            c10=fmaf(px1,py0,c10); c11=fmaf(px1,py1,c11); c12=fmaf(px1,py2,c12);
            c20=fmaf(px2,py0,c20); c21=fmaf(px2,py1,c21); c22=fmaf(px2,py2,c22);
        }
        {
            float px0=xB.y, px1=xC.x, px2=xC.y;
            float py0=yB.y, py1=yC.x, py2=yC.y;
            sx0+=px0; sx1+=px1; sx2+=px2;
            sy0+=py0; sy1+=py1; sy2+=py2;
            qx = fmaf(px0,px0,fmaf(px1,px1,fmaf(px2,px2,qx)));
            qy = fmaf(py0,py0,fmaf(py1,py1,fmaf(py2,py2,qy)));
            c00=fmaf(px0,py0,c00); c01=fmaf(px0,py1,c01); c02=fmaf(px0,py2,c02);
            c10=fmaf(px1,py0,c10); c11=fmaf(px1,py1,c11); c12=fmaf(px1,py2,c12);
            c20=fmaf(px2,py0,c20); c21=fmaf(px2,py1,c21); c22=fmaf(px2,py2,c22);
        }
    }

    // Butterfly reduce the 17 sums within each 8-lane group (masks 1,2,4).
    #pragma unroll
    for (int m = 1; m <= 4; m <<= 1) {
        sx0=xsum(sx0,m); sx1=xsum(sx1,m); sx2=xsum(sx2,m);
        sy0=xsum(sy0,m); sy1=xsum(sy1,m); sy2=xsum(sy2,m);
        qx =xsum(qx ,m); qy =xsum(qy ,m);
        c00=xsum(c00,m); c01=xsum(c01,m); c02=xsum(c02,m);
        c10=xsum(c10,m); c11=xsum(c11,m); c12=xsum(c12,m);
        c20=xsum(c20,m); c21=xsum(c21,m); c22=xsum(c22,m);
    }
    // Now every lane in a group holds its batch's full sums.

    const float invN = 1.0f / (float)NPTS;
    // Mean-centered covariance C = Sxy - sx sy^T / N
    float C00 = c00 - sx0*sy0*invN, C01 = c01 - sx0*sy1*invN, C02 = c02 - sx0*sy2*invN;
    float C10 = c10 - sx1*sy0*invN, C11 = c11 - sx1*sy1*invN, C12 = c12 - sx1*sy2*invN;
    float C20 = c20 - sx2*sy0*invN, C21 = c21 - sx2*sy1*invN, C22 = c22 - sx2*sy2*invN;
    float Sx = qx - (sx0*sx0 + sx1*sx1 + sx2*sx2) * invN;
    float Sy = qy - (sy0*sy0 + sy1*sy1 + sy2*sy2) * invN;

    // A = C^T C (symmetric PSD); closed-form eigenvalues (trigonometric).
    float a00 = C00*C00 + C10*C10 + C20*C20;
    float a01 = C00*C01 + C10*C11 + C20*C21;
    float a02 = C00*C02 + C10*C12 + C20*C22;
    float a11 = C01*C01 + C11*C11 + C21*C21;
    float a12 = C01*C02 + C11*C12 + C21*C22;
    float a22 = C02*C02 + C12*C12 + C22*C22;

    float q = (a00 + a11 + a22) * (1.0f / 3.0f);
    float b00 = a00 - q, b11 = a11 - q, b22 = a22 - q;
    float p2 = (b00*b00 + b11*b11 + b22*b22
                + 2.0f * (a01*a01 + a02*a02 + a12*a12)) * (1.0f / 6.0f);
    float p = sqrtf(fmaxf(p2, 0.0f));
    float detB = b00 * (b11*b22 - a12*a12)
               - a01 * (a01*b22 - a12*a02)
               + a02 * (a01*a12 - b11*a02);
    float p3 = p * p * p;
    float r = (p3 > 1e-30f) ? (0.5f * detB / p3) : 0.0f;
    r = fminf(1.0f, fmaxf(-1.0f, r));
    float phi = acosf(r) * (1.0f / 3.0f);
    float two_p = 2.0f * p;
    float l1 = q + two_p * cosf(phi);                        // largest
    float l3 = q + two_p * cosf(phi + 2.0943951023931953f);  // smallest
    float l2 = 3.0f * q - l1 - l3;
    float nuc = sqrtf(fmaxf(l1, 0.0f)) + sqrtf(fmaxf(l2, 0.0f)) + sqrtf(fmaxf(l3, 0.0f));

    float term = Sx + Sy - 2.0f * nuc;

    // Sum the 8 distinct group terms across the wave (masks 8,16,32).
    term += __shfl_xor(term, 8);
    term += __shfl_xor(term, 16);
    term += __shfl_xor(term, 32);

    __shared__ float wsum[4];
    if (lane == 0) wsum[wave] = term;
    __syncthreads();
    if (tid == 0) {
        float t = (wsum[0] + wsum[1] + wsum[2] + wsum[3]) * scale;
        atomicAdd(out, t);
    }
}

extern "C" void kernel_launch(void* const* d_in, const int* in_sizes, int n_in,
                              void* d_out, int out_size, void* d_ws, size_t ws_size,
                              hipStream_t stream) {
    const float* x = (const float*)d_in[0];
    const float* y = (const float*)d_in[1];
    float* out = (float*)d_out;

    const int B = in_sizes[0] / (NPTS * 3);   // 65536
    const float scale = 1.0f / ((float)B * (float)NPTS * 3.0f);

    hipMemsetAsync(out, 0, sizeof(float), stream);   // harness poisons d_out
    const int blocks = B / 32;                       // 32 batches per 256-thread block
    kabsch_kernel<<<blocks, 256, 0, stream>>>(x, y, out, scale);
}